// Round 5
// baseline (49.455 us; speedup 1.0000x reference)
//
#include <hip/hip_runtime.h>

// Spatial transformer, bilinear sampling, NCHW fp32.
// X: (B, C, H, W) = (32, 3, 512, 512), theta: (B, 6), out: (B, C, H, W).
//
// R5: 2 horizontal px/thread sharing ONE dwordx4 gather per row per channel
//     (corner pairs of adjacent px overlap since dx/dw = t00 ~ 1). Rare
//     mismatch lanes (row change between px, |step|>2, right edge) take a
//     predicated dwordx2 path. dwordx2 nt stores. f32 linspace (bilinear
//     interpolant is continuous -> 1e-7 coord perturbation is harmless).
//     Keeps: lane-contiguous mapping, nt stores, XCD-contiguous swizzle.

#define ST_H 512
#define ST_W 512
#define ST_C 3
#define ST_HW (ST_H * ST_W)

typedef float f2 __attribute__((ext_vector_type(2)));
typedef float f4 __attribute__((ext_vector_type(4)));
struct __attribute__((packed, aligned(4))) f2_a4 { f2 v; };
struct __attribute__((packed, aligned(4))) f4_a4 { f4 v; };

__device__ __forceinline__ float pick3(f4 v, int o) {   // v[o], o in {0,1,2}
    float r = v.x;
    r = (o == 1) ? v.y : r;
    r = (o == 2) ? v.z : r;
    return r;
}
__device__ __forceinline__ float pick3h(f4 v, int o) {  // v[o+1], o in {0,1,2}
    float r = v.y;
    r = (o == 1) ? v.z : r;
    r = (o == 2) ? v.w : r;
    return r;
}

__global__ __launch_bounds__(256) void st_bilinear_kernel(
    const float* __restrict__ X,
    const float* __restrict__ theta,
    float* __restrict__ out,
    int B, int chunk)
{
    // XCD swizzle: each XCD owns a contiguous range of blocks (grid % 8 == 0).
    int bid = blockIdx.x;
    bid = (bid & 7) * chunk + (bid >> 3);

    const int h  = bid & (ST_H - 1);     // one block = one output row
    const int b  = bid >> 9;
    const int w0 = (int)threadIdx.x * 2; // 2 consecutive px per thread

    const float* t = theta + b * 6;
    const float t00 = t[0], t01 = t[1], t02 = t[2];
    const float t10 = t[3], t11 = t[4], t12 = t[5];

    const float STEP = (float)(2.0 / 511.0);
    const float yg = fmaf((float)h, STEP, -1.0f);
    const float cx = fmaf(t01, yg, t02);
    const float cy = fmaf(t11, yg, t12);

    float wa[2], wbm[2], wcm[2], wdm[2];
    int xa[2], ta[2], tb[2];
    bool hi[2], lo[2];

#pragma unroll
    for (int j = 0; j < 2; ++j) {
        const float xg = fmaf((float)(w0 + j), STEP, -1.0f);
        const float x = (fmaf(t00, xg, cx) + 1.0f) * 256.0f;
        const float y = (fmaf(t10, xg, cy) + 1.0f) * 256.0f;
        const int x0 = (int)floorf(x);
        const int y0 = (int)floorf(y);
        const int x0c = min(max(x0, 0), ST_W - 1);
        const int x1c = min(max(x0 + 1, 0), ST_W - 1);
        const int y0c = min(max(y0, 0), ST_H - 1);
        const int y1c = min(max(y0 + 1, 0), ST_H - 1);
        // weights use CLIPPED coords cast to float (reference semantics)
        const float x0f = (float)x0c, x1f = (float)x1c;
        const float y0f = (float)y0c, y1f = (float)y1c;
        wa[j]  = (x1f - x) * (y1f - y);
        wbm[j] = (x1f - x) * (y - y0f);
        wcm[j] = (x - x0f) * (y1f - y);
        wdm[j] = (x - x0f) * (y - y0f);
        xa[j] = min(max(x0, 0), ST_W - 2);   // pair-gather start col
        ta[j] = y0c;
        tb[j] = y1c;
        hi[j] = (x0 >= ST_W - 1);
        lo[j] = (x0 < 0);
    }

    // shared dwordx4 covers cols [base, base+3]; base<=508 keeps it in-plane
    const int  base = min(xa[0], ST_W - 4);
    const bool g0 = (xa[0] <= ST_W - 4);                 // px0 at v[0],v[1]
    const int  o1 = xa[1] - base;
    const bool g1 = ((unsigned)o1 <= 2u) && (ta[1] == ta[0]) && (tb[1] == tb[0]);

    const float* __restrict__ Xb = X + (size_t)b * (ST_C * ST_HW);
    float* __restrict__ ob = out + (size_t)b * (ST_C * ST_HW) + h * ST_W + w0;

#pragma unroll
    for (int c = 0; c < ST_C; ++c) {
        const float* __restrict__ Xc = Xb + c * ST_HW;
        const f4 va = ((const f4_a4*)(Xc + ta[0] * ST_W + base))->v;
        const f4 vb = ((const f4_a4*)(Xc + tb[0] * ST_W + base))->v;

        float pA0, pC0, pB0, pD0;
        if (g0) {
            pA0 = va.x; pC0 = va.y; pB0 = vb.x; pD0 = vb.y;
        } else {  // rare: right edge, xa0 in {509,510}
            const f2 p = ((const f2_a4*)(Xc + ta[0] * ST_W + xa[0]))->v;
            const f2 q = ((const f2_a4*)(Xc + tb[0] * ST_W + xa[0]))->v;
            pA0 = p.x; pC0 = p.y; pB0 = q.x; pD0 = q.y;
        }

        float pA1, pC1, pB1, pD1;
        if (g1) {
            pA1 = pick3 (va, o1); pC1 = pick3h(va, o1);
            pB1 = pick3 (vb, o1); pD1 = pick3h(vb, o1);
        } else {  // rare: row step between px, |dx|>2, or border collapse
            const f2 p = ((const f2_a4*)(Xc + ta[1] * ST_W + xa[1]))->v;
            const f2 q = ((const f2_a4*)(Xc + tb[1] * ST_W + xa[1]))->v;
            pA1 = p.x; pC1 = p.y; pB1 = q.x; pD1 = q.y;
        }

        // border selects (clipped-gather semantics, as R4)
        const float Ia0 = hi[0] ? pC0 : pA0;
        const float Ic0 = lo[0] ? pA0 : pC0;
        const float Ib0 = hi[0] ? pD0 : pB0;
        const float Id0 = lo[0] ? pB0 : pD0;
        const float Ia1 = hi[1] ? pC1 : pA1;
        const float Ic1 = lo[1] ? pA1 : pC1;
        const float Ib1 = hi[1] ? pD1 : pB1;
        const float Id1 = lo[1] ? pB1 : pD1;

        f2 v;
        v.x = wa[0] * Ia0 + wbm[0] * Ib0 + wcm[0] * Ic0 + wdm[0] * Id0;
        v.y = wa[1] * Ia1 + wbm[1] * Ib1 + wcm[1] * Ic1 + wdm[1] * Id1;
        // nontemporal: output has zero reuse; keep L2/L3 for the gathers
        __builtin_nontemporal_store(v, (f2*)(ob + c * ST_HW));
    }
    (void)B;
}

extern "C" void kernel_launch(void* const* d_in, const int* in_sizes, int n_in,
                              void* d_out, int out_size, void* d_ws, size_t ws_size,
                              hipStream_t stream) {
    const float* X     = (const float*)d_in[0];
    const float* theta = (const float*)d_in[1];
    float* out         = (float*)d_out;

    const int B = in_sizes[1] / 6;              // 32
    const int block = 256;                      // 512 px = one row per block
    const int grid = B * ST_H;                  // 16384, divisible by 8
    const int chunk = grid / 8;                 // blocks per XCD

    st_bilinear_kernel<<<grid, block, 0, stream>>>(X, theta, out, B, chunk);
}